// Round 3
// baseline (312.705 us; speedup 1.0000x reference)
//
#include <hip/hip_runtime.h>

typedef __attribute__((ext_vector_type(8))) short short8;
typedef __attribute__((ext_vector_type(4))) float f32x4;

__device__ __forceinline__ unsigned short f32_to_bf16(float f) {
    union { float f; unsigned int u; } c; c.f = f;
    unsigned int u = c.u;
    // round-to-nearest-even
    unsigned int r = (u + 0x7fffu + ((u >> 16) & 1u)) >> 16;
    return (unsigned short)r;
}

// Normalize rows of [nA+nB, 128] fp32 -> bf16 rows scaled by 3/||v||, plus
// sq-norm output sout[row] = 9*sq*r^2 (== sum(x*x) to ~1e-6).
// Rows [0, nA) come from inA, rows [nA, nA+nB) from inB (outputs are
// contiguous in the workspace, so one fused dispatch covers both).
// One wave per row, 4 waves per block.
__global__ void norm_kernel(const float* __restrict__ inA,
                            const float* __restrict__ inB,
                            int nA,
                            unsigned short* __restrict__ xout,
                            float* __restrict__ sout) {
    const int row  = blockIdx.x * 4 + (threadIdx.x >> 6);
    const int lane = threadIdx.x & 63;
    const float* src = (row < nA) ? (inA + (size_t)row * 128)
                                  : (inB + (size_t)(row - nA) * 128);
    const float2 v = ((const float2*)src)[lane];
    float s = fmaf(v.x, v.x, v.y * v.y);
#pragma unroll
    for (int off = 32; off; off >>= 1) s += __shfl_xor(s, off, 64);
    const float r  = rsqrtf(fmaxf(s, 1e-12f));
    const float sc = 3.0f * r;
    ushort2 o;
    o.x = f32_to_bf16(v.x * sc);
    o.y = f32_to_bf16(v.y * sc);
    ((ushort2*)(xout + (size_t)row * 128))[lane] = o;
    if (lane == 0) sout[row] = 9.0f * s * (r * r);
}

// C = xs[b] + ps[c] - 2 * A*B^T, A:[M,128] bf16 row-major, B:[N,128] bf16 row-major.
// NO LDS, NO BARRIER: operands total 5 MB (L2/L3-resident), so LDS staging +
// the __syncthreads vmcnt(0) drain was pure overhead (Common-mistake #7).
// Each wave loads its MFMA fragments directly global->VGPR: for a fragment,
// lanes 0..63 cover 16 rows x 64B of fully-covered cache lines (same
// coalescing the staging loop had). Waves are fully independent streaming
// pipelines (load -> mfma -> store), no cross-wave sync, 3 blocks/CU.
//
// MFMA operands are SWAPPED (P-frag in A-role) so the D fragment is
// transposed: lane holds out[b = ..+l15][c = ..+quad*4+r] -> dwordx4 stores.
// Output (256 MiB) is never re-read -> nontemporal stores keep it from
// thrashing the L2 copy of A/B.
__global__ __launch_bounds__(256, 3) void gemm_kernel(
    const unsigned short* __restrict__ A,
    const unsigned short* __restrict__ B,
    const float* __restrict__ xs,
    const float* __restrict__ ps,
    float* __restrict__ out,
    int Ncols)
{
    const int tid  = threadIdx.x;
    const int lane = tid & 63;
    const int wave = tid >> 6;
    const int bm   = blockIdx.y;
    const int bn   = blockIdx.x;

    const int wm   = (wave >> 1) * 64;  // wave's row offset in 128x128 tile
    const int wn   = (wave & 1) * 64;   // wave's col offset
    const int l15  = lane & 15;
    const int quad = lane >> 4;

    // xs/ps for the epilogue (L1/L2 hits, issued early).
    float xsr[4];
    float psr[16];
#pragma unroll
    for (int mt = 0; mt < 4; ++mt)
        xsr[mt] = xs[bm * 128 + wm + mt * 16 + l15];
#pragma unroll
    for (int nt = 0; nt < 4; ++nt)
#pragma unroll
        for (int r = 0; r < 4; ++r)
            psr[nt * 4 + r] = ps[bn * 128 + wn + nt * 16 + quad * 4 + r];

    // Wave's operand panels. Per-lane element offset within a panel row
    // group: row l15 (stride 128 elems), k-chunk quad (8 elems).
    const unsigned short* Ab = A + (size_t)(bm * 128 + wm) * 128;
    const unsigned short* Bb = B + (size_t)(bn * 128 + wn) * 128;
    const int loff = l15 * 128 + quad * 8;

    f32x4 acc[4][4];
#pragma unroll
    for (int i = 0; i < 4; ++i)
#pragma unroll
        for (int j = 0; j < 4; ++j)
            acc[i][j] = (f32x4){0.f, 0.f, 0.f, 0.f};

    // K = 128 -> 4 MFMA k-steps of 32. Fragment (t, kk) = 16B at
    // row (t*16 + l15), elems [kk*32 + quad*8, +8). Fully unrolled; the
    // compiler pipelines next-kk loads over current-kk MFMAs.
#pragma unroll
    for (int kk = 0; kk < 4; ++kk) {
        short8 af[4], bfv[4];
#pragma unroll
        for (int t = 0; t < 4; ++t) {
            af[t]  = *(const short8*)(Ab + t * 16 * 128 + kk * 32 + loff);
            bfv[t] = *(const short8*)(Bb + t * 16 * 128 + kk * 32 + loff);
        }
        // swapped operand order: D = P_frag * X_frag^T -> transposed C layout
#pragma unroll
        for (int mt = 0; mt < 4; ++mt)
#pragma unroll
            for (int nt = 0; nt < 4; ++nt)
                acc[mt][nt] = __builtin_amdgcn_mfma_f32_16x16x32_bf16(
                    bfv[nt], af[mt], acc[mt][nt], 0, 0, 0);
    }

    // --- epilogue: out = xs[b] + ps[c] - 2*dot, one nontemporal dwordx4
    // store per fragment (16 rows x 64B fully-covered lines per instr).
    const size_t stride = (size_t)Ncols;
#pragma unroll
    for (int mt = 0; mt < 4; ++mt) {
        const int grow = bm * 128 + wm + mt * 16 + l15;   // global out row (b)
        float* orow = out + (size_t)grow * stride;
#pragma unroll
        for (int nt = 0; nt < 4; ++nt) {
            const int gcol = bn * 128 + wn + nt * 16 + quad * 4;  // 16B aligned
            f32x4 v;
#pragma unroll
            for (int r = 0; r < 4; ++r)
                v[r] = fmaf(-2.0f, acc[mt][nt][r], xsr[mt] + psr[nt * 4 + r]);
            __builtin_nontemporal_store(v, (f32x4*)(orow + gcol));
        }
    }
}

extern "C" void kernel_launch(void* const* d_in, const int* in_sizes, int n_in,
                              void* d_out, int out_size, void* d_ws, size_t ws_size,
                              hipStream_t stream) {
    const float* inputs = (const float*)d_in[0];
    const float* kern   = (const float*)d_in[1];
    float* out          = (float*)d_out;

    const int D = 128;
    const int B = in_sizes[0] / D;   // 4096
    const int C = in_sizes[1] / D;   // 16384

    char* ws = (char*)d_ws;
    unsigned short* xA = (unsigned short*)ws;                       // B*D bf16
    unsigned short* pB = (unsigned short*)(ws + (size_t)B * D * 2); // C*D bf16
    float* xs = (float*)(ws + (size_t)(B + C) * D * 2);             // B floats
    float* ps = xs + B;                                             // C floats

    // One fused norm dispatch: rows [0,B) from inputs, [B, B+C) from kern.
    norm_kernel<<<(B + C) / 4, 256, 0, stream>>>(inputs, kern, B, xA, xs);

    dim3 grid(C / 128, B / 128);  // 128 x 32 = 4096 blocks
    gemm_kernel<<<grid, 256, 0, stream>>>(xA, pB, xs, ps, out, C);
}